// Round 3
// baseline (54.376 us; speedup 1.0000x reference)
//
#include <hip/hip_runtime.h>

// Problem constants (fixed by the reference)
#define NXY   16
#define NZ    8
#define NS    2048      // states = 16*16*8
#define NT    2048      // tokens
#define NB    16        // stories
#define NL    16        // story length
#define NSENT 16        // tokens per sentence
#define NEGV  (-1e9f)

// ---------------------------------------------------------------------------
// K1: fused smoothing + transpose.
// Identity: windowed log-mean along x then y ==
//           log( boxmean_y( boxmean_x( exp(em) ) ) )
// exp once at load, two 5-term box sums (replicate-clamped), one log at the
// transposed write. TT=8 -> 2048 blocks (8/CU) for latency hiding.
// ---------------------------------------------------------------------------
#define TT   8
#define LPAD 9           // odd pad -> conflict-free stride

__global__ __launch_bounds__(256) void k_smooth(const float* __restrict__ em,
                                                float* __restrict__ emT) {
    __shared__ float A[256 * LPAD];   // 9 KB
    const int tid = threadIdx.x;
    const int t0 = blockIdx.x * TT;
    const int z = blockIdx.y;

    // load 256 (y,x) rows x 8 tokens, float4-coalesced, exp at store
    const float* base = em + (size_t)z * 256 * NT + t0;
#pragma unroll
    for (int i = 0; i < 2; ++i) {
        int f = (i * 256 + tid) * 4;
        int xy = f >> 3;
        int c = f & 7;
        float4 v = *(const float4*)(base + (size_t)xy * NT + c);
        float* dst = &A[xy * LPAD + c];
        dst[0] = __expf(v.x); dst[1] = __expf(v.y);
        dst[2] = __expf(v.z); dst[3] = __expf(v.w);
    }
    __syncthreads();

    const int x = tid & 15, y = tid >> 4;

    // x-pass: 5-term box sum into registers
    int r[5];
#pragma unroll
    for (int k = 0; k < 5; ++k) {
        int xx = x + k - 2; xx = xx < 0 ? 0 : (xx > 15 ? 15 : xx);
        r[k] = (y * 16 + xx) * LPAD;
    }
    float rx[TT];
#pragma unroll
    for (int tt = 0; tt < TT; ++tt)
        rx[tt] = A[r[0] + tt] + A[r[1] + tt] + A[r[2] + tt] + A[r[3] + tt] + A[r[4] + tt];
    __syncthreads();

    // write back in place
#pragma unroll
    for (int tt = 0; tt < TT; ++tt) A[tid * LPAD + tt] = rx[tt];
    __syncthreads();

    // y-pass + log + transposed write
#pragma unroll
    for (int k = 0; k < 5; ++k) {
        int yy = y + k - 2; yy = yy < 0 ? 0 : (yy > 15 ? 15 : yy);
        r[k] = (yy * 16 + x) * LPAD;
    }
    const float LOG25 = 3.2188758248682006f;   // log(5)+log(5)
    float* ob = emT + (size_t)t0 * NS + z * 256 + tid;
#pragma unroll
    for (int tt = 0; tt < TT; ++tt) {
        float s = A[r[0] + tt] + A[r[1] + tt] + A[r[2] + tt] + A[r[3] + tt] + A[r[4] + tt];
        ob[(size_t)tt * NS] = __logf(s) - LOG25;
    }
}

// ---------------------------------------------------------------------------
// K2: e_all[b,l,s] = sum_j em_T[tok[b,l,j], s]   (contiguous row reads)
// grid (256 sentences, 2 halves of the state vector)
// ---------------------------------------------------------------------------
__global__ __launch_bounds__(256) void k_eall(const int* __restrict__ stories,
                                              const float* __restrict__ emT,
                                              float* __restrict__ eall) {
    const int bl = blockIdx.x;          // b*NL + l
    const int col = blockIdx.y * 256 + threadIdx.x;   // float4 index, 0..511
    __shared__ int toks[NSENT];
    if (threadIdx.x < NSENT) toks[threadIdx.x] = stories[bl * NSENT + threadIdx.x];
    __syncthreads();

    float4 a = make_float4(0.f, 0.f, 0.f, 0.f);
#pragma unroll 4
    for (int j = 0; j < NSENT; ++j) {
        float4 v = ((const float4*)(emT + (size_t)toks[j] * NS))[col];
        a.x += v.x; a.y += v.y; a.z += v.z; a.w += v.w;
    }
    ((float4*)(eall + (size_t)bl * NS))[col] = a;
}

// ---------------------------------------------------------------------------
// K3: forward recursion, one block per story; 512 threads x 4 states (4-way
// ILP). Weights + clamped neighbor indices in registers. Output stores are
// deferred one iteration (issued at the top of the next step from registers)
// so the pre-barrier vmcnt(0) drain overlaps compute; next step's e row is
// prefetched one iteration early.
// ---------------------------------------------------------------------------
__global__ __launch_bounds__(512) void k_forward(const float* __restrict__ trans,
                                                 const float* __restrict__ priors,
                                                 const float* __restrict__ eall,
                                                 float* __restrict__ out) {
    __shared__ float buf0[NS];      // 8 KB
    __shared__ float buf1[NS];      // 8 KB
    const int b = blockIdx.x;
    const int tid = threadIdx.x;
    const float* eb = eall + (size_t)b * NL * NS;

    float wr[4][7];
    int   ix[4][7];
    float e_cur[4], vres[4];
#pragma unroll
    for (int p = 0; p < 4; ++p) {
        const int h = tid + p * 512;
        const int x = h & 15, y = (h >> 4) & 15, z = h >> 8;
        const float* row = trans + (size_t)h * NS;
        wr[p][0] = row[h];                          ix[p][0] = h;
        wr[p][1] = (x < 15) ? row[h + 1]   : NEGV;  ix[p][1] = (x < 15) ? h + 1   : h;
        wr[p][2] = (x > 0)  ? row[h - 1]   : NEGV;  ix[p][2] = (x > 0)  ? h - 1   : h;
        wr[p][3] = (y < 15) ? row[h + 16]  : NEGV;  ix[p][3] = (y < 15) ? h + 16  : h;
        wr[p][4] = (y > 0)  ? row[h - 16]  : NEGV;  ix[p][4] = (y > 0)  ? h - 16  : h;
        wr[p][5] = (z < 7)  ? row[h + 256] : NEGV;  ix[p][5] = (z < 7)  ? h + 256 : h;
        wr[p][6] = (z < 6)  ? row[h + 512] : NEGV;  ix[p][6] = (z < 6)  ? h + 512 : h;
        float v = eb[h] + priors[h];
        buf0[h] = v;
        vres[p] = v;                 // out[0][b][h], stored at top of l=1
        e_cur[p] = eb[NS + h];       // prefetch e for step 1
    }
    __syncthreads();

    float* prev = buf0;
    float* cur = buf1;
    for (int l = 1; l < NL; ++l) {
        // deferred store of step l-1's result (registers -> global, overlaps
        // this step's compute; drained by this step's barrier)
#pragma unroll
        for (int p = 0; p < 4; ++p)
            out[((size_t)(l - 1) * NB + b) * NS + tid + p * 512] = vres[p];

        // prefetch next step's e row
        float e_nxt[4] = {0.f, 0.f, 0.f, 0.f};
        if (l + 1 < NL) {
#pragma unroll
            for (int p = 0; p < 4; ++p)
                e_nxt[p] = eb[(size_t)(l + 1) * NS + tid + p * 512];
        }

#pragma unroll
        for (int p = 0; p < 4; ++p) {
            const int h = tid + p * 512;
            float v0 = wr[p][0] + prev[ix[p][0]];
            float v1 = wr[p][1] + prev[ix[p][1]];
            float v2 = wr[p][2] + prev[ix[p][2]];
            float v3 = wr[p][3] + prev[ix[p][3]];
            float v4 = wr[p][4] + prev[ix[p][4]];
            float v5 = wr[p][5] + prev[ix[p][5]];
            float v6 = wr[p][6] + prev[ix[p][6]];
            float m = fmaxf(fmaxf(fmaxf(v0, v1), fmaxf(v2, v3)),
                            fmaxf(fmaxf(v4, v5), v6));
            float s = __expf(v0 - m) + __expf(v1 - m) + __expf(v2 - m) + __expf(v3 - m) +
                      __expf(v4 - m) + __expf(v5 - m) + __expf(v6 - m);
            float v = e_cur[p] + m + __logf(s);
            cur[h] = v;
            vres[p] = v;
        }
        __syncthreads();
#pragma unroll
        for (int p = 0; p < 4; ++p) e_cur[p] = e_nxt[p];
        float* tmp = prev; prev = cur; cur = tmp;
    }

    // final step's result
#pragma unroll
    for (int p = 0; p < 4; ++p)
        out[((size_t)(NL - 1) * NB + b) * NS + tid + p * 512] = vres[p];
}

// ---------------------------------------------------------------------------
extern "C" void kernel_launch(void* const* d_in, const int* in_sizes, int n_in,
                              void* d_out, int out_size, void* d_ws, size_t ws_size,
                              hipStream_t stream) {
    (void)in_sizes; (void)n_in; (void)out_size; (void)ws_size;
    const int* stories  = (const int*)d_in[0];
    // d_in[1] = story_length (== NL), unused
    const float* priors = (const float*)d_in[2];
    const float* trans  = (const float*)d_in[3];
    const float* em     = (const float*)d_in[4];
    float* out = (float*)d_out;

    float* emT  = (float*)d_ws;                    // [NT][NS]  16 MB
    float* eall = emT + (size_t)NT * NS;           // [NB*NL][NS]  2 MB

    k_smooth<<<dim3(NT / TT, NZ), 256, 0, stream>>>(em, emT);
    k_eall<<<dim3(NB * NL, 2), 256, 0, stream>>>(stories, emT, eall);
    k_forward<<<dim3(NB), 512, 0, stream>>>(trans, priors, eall, out);
}

// Round 4
// 53.276 us; speedup vs baseline: 1.0207x; 1.0207x over previous
//
#include <hip/hip_runtime.h>

// Problem constants (fixed by the reference)
#define NXY   16
#define NZ    8
#define NS    2048      // states = 16*16*8
#define NT    2048      // tokens
#define NB    16        // stories
#define NL    16        // story length
#define NSENT 16        // tokens per sentence
#define NEGV  (-1e9f)

// ---------------------------------------------------------------------------
// Smoothing identity: windowed log-mean along x then y ==
//   log( boxsum_y( boxsum_x( exp(em) ) ) ) - log 25
//
// Pass A: exp + clamped 5-wide x-box-sum entirely in registers, native
// [s][t] layout, lane = token -> fully coalesced, no LDS, no barriers.
// ---------------------------------------------------------------------------
__global__ __launch_bounds__(256) void k_smoothA(const float* __restrict__ em,
                                                 float* __restrict__ xs) {
    const int tid = threadIdx.x;
    const int tc  = blockIdx.x;          // 8 chunks of 256 tokens
    const int zy  = blockIdx.y;          // z*16 + y, 128 rows-of-16
    const size_t rowbase = (size_t)zy * 16 * NT + tc * 256 + tid;

    float ex[16];
#pragma unroll
    for (int x = 0; x < 16; ++x)
        ex[x] = __expf(em[rowbase + (size_t)x * NT]);

#pragma unroll
    for (int x = 0; x < 16; ++x) {
        const int xm2 = x - 2 < 0 ? 0 : x - 2, xm1 = x - 1 < 0 ? 0 : x - 1;
        const int xp1 = x + 1 > 15 ? 15 : x + 1, xp2 = x + 2 > 15 ? 15 : x + 2;
        xs[rowbase + (size_t)x * NT] = ex[xm2] + ex[xm1] + ex[x] + ex[xp1] + ex[xp2];
    }
}

// ---------------------------------------------------------------------------
// Pass B: clamped 5-wide y-box-sum (rows at s +/- 16,32 within the z-slice,
// coalesced reads from L2/L3-resident xs) + log + LDS-tiled transpose ->
// emT[t][s] written coalesced. 64x64 tile, pad-65 LDS (2-way = free).
// ---------------------------------------------------------------------------
__global__ __launch_bounds__(256) void k_smoothB(const float* __restrict__ xs,
                                                 float* __restrict__ emT) {
    __shared__ float L[64 * 65];
    const int tid = threadIdx.x;
    const int j   = tid & 63;            // token within tile
    const int si  = tid >> 6;            // s sub-group
    const int t0  = blockIdx.x * 64;
    const int s0  = blockIdx.y * 64;
    const float LOG25 = 3.2188758248682006f;

#pragma unroll
    for (int i = 0; i < 16; ++i) {
        const int srow = s0 + si * 16 + i;
        const int y = (srow >> 4) & 15;
        float acc = 0.f;
#pragma unroll
        for (int k = -2; k <= 2; ++k) {
            int yc = y + k; yc = yc < 0 ? 0 : (yc > 15 ? 15 : yc);
            acc += xs[(size_t)(srow + (yc - y) * 16) * NT + t0 + j];
        }
        L[(si * 16 + i) * 65 + j] = __logf(acc) - LOG25;
    }
    __syncthreads();

#pragma unroll
    for (int i = 0; i < 16; ++i) {
        const int trow = t0 + si * 16 + i;
        emT[(size_t)trow * NS + s0 + j] = L[j * 65 + si * 16 + i];
    }
}

// ---------------------------------------------------------------------------
// Fallback single-kernel smooth (round-2 version) if workspace is too small
// for the xs intermediate.
// ---------------------------------------------------------------------------
#define TT   16
#define LPAD 17

__global__ __launch_bounds__(256) void k_smooth(const float* __restrict__ em,
                                                float* __restrict__ emT) {
    __shared__ float A[256 * LPAD];
    const int tid = threadIdx.x;
    const int t0 = blockIdx.x * TT;
    const int z = blockIdx.y;

    const float* base = em + (size_t)z * 256 * NT + t0;
#pragma unroll
    for (int i = 0; i < 4; ++i) {
        int f = (i * 256 + tid) * 4;
        int xy = f >> 4;
        int c = f & 15;
        float4 v = *(const float4*)(base + (size_t)xy * NT + c);
        float* dst = &A[xy * LPAD + c];
        dst[0] = __expf(v.x); dst[1] = __expf(v.y);
        dst[2] = __expf(v.z); dst[3] = __expf(v.w);
    }
    __syncthreads();

    const int x = tid & 15, y = tid >> 4;
    int r[5];
#pragma unroll
    for (int k = 0; k < 5; ++k) {
        int xx = x + k - 2; xx = xx < 0 ? 0 : (xx > 15 ? 15 : xx);
        r[k] = (y * 16 + xx) * LPAD;
    }
    float rx[TT];
#pragma unroll
    for (int tt = 0; tt < TT; ++tt)
        rx[tt] = A[r[0] + tt] + A[r[1] + tt] + A[r[2] + tt] + A[r[3] + tt] + A[r[4] + tt];
    __syncthreads();
#pragma unroll
    for (int tt = 0; tt < TT; ++tt) A[tid * LPAD + tt] = rx[tt];
    __syncthreads();
#pragma unroll
    for (int k = 0; k < 5; ++k) {
        int yy = y + k - 2; yy = yy < 0 ? 0 : (yy > 15 ? 15 : yy);
        r[k] = (yy * 16 + x) * LPAD;
    }
    const float LOG25 = 3.2188758248682006f;
    float* ob = emT + (size_t)t0 * NS + z * 256 + tid;
#pragma unroll
    for (int tt = 0; tt < TT; ++tt) {
        float s = A[r[0] + tt] + A[r[1] + tt] + A[r[2] + tt] + A[r[3] + tt] + A[r[4] + tt];
        ob[(size_t)tt * NS] = __logf(s) - LOG25;
    }
}

// ---------------------------------------------------------------------------
// K2: e_all[b,l,s] = sum_j em_T[tok[b,l,j], s]   (contiguous row reads)
// ---------------------------------------------------------------------------
__global__ __launch_bounds__(256) void k_eall(const int* __restrict__ stories,
                                              const float* __restrict__ emT,
                                              float* __restrict__ eall) {
    const int bl = blockIdx.x;
    const int col = blockIdx.y * 256 + threadIdx.x;
    __shared__ int toks[NSENT];
    if (threadIdx.x < NSENT) toks[threadIdx.x] = stories[bl * NSENT + threadIdx.x];
    __syncthreads();

    float4 a = make_float4(0.f, 0.f, 0.f, 0.f);
#pragma unroll 4
    for (int j = 0; j < NSENT; ++j) {
        float4 v = ((const float4*)(emT + (size_t)toks[j] * NS))[col];
        a.x += v.x; a.y += v.y; a.z += v.z; a.w += v.w;
    }
    ((float4*)(eall + (size_t)bl * NS))[col] = a;
}

// ---------------------------------------------------------------------------
// K3: forward recursion (round-2 proven version): one block per story,
// 1024 threads x 2 states, weights + clamped indices in registers,
// prev/cur ping-pong in LDS.
// ---------------------------------------------------------------------------
__global__ __launch_bounds__(1024) void k_forward(const float* __restrict__ trans,
                                                  const float* __restrict__ priors,
                                                  const float* __restrict__ eall,
                                                  float* __restrict__ out) {
    __shared__ float buf0[NS];
    __shared__ float buf1[NS];
    const int b = blockIdx.x;
    const int tid = threadIdx.x;

    float wr[2][7];
    int   ix[2][7];
#pragma unroll
    for (int p = 0; p < 2; ++p) {
        const int h = tid + p * 1024;
        const int x = h & 15, y = (h >> 4) & 15, z = h >> 8;
        const float* row = trans + (size_t)h * NS;
        wr[p][0] = row[h];                          ix[p][0] = h;
        wr[p][1] = (x < 15) ? row[h + 1]   : NEGV;  ix[p][1] = (x < 15) ? h + 1   : h;
        wr[p][2] = (x > 0)  ? row[h - 1]   : NEGV;  ix[p][2] = (x > 0)  ? h - 1   : h;
        wr[p][3] = (y < 15) ? row[h + 16]  : NEGV;  ix[p][3] = (y < 15) ? h + 16  : h;
        wr[p][4] = (y > 0)  ? row[h - 16]  : NEGV;  ix[p][4] = (y > 0)  ? h - 16  : h;
        wr[p][5] = (z < 7)  ? row[h + 256] : NEGV;  ix[p][5] = (z < 7)  ? h + 256 : h;
        wr[p][6] = (z < 6)  ? row[h + 512] : NEGV;  ix[p][6] = (z < 6)  ? h + 512 : h;
        float v = eall[(size_t)b * NL * NS + h] + priors[h];
        buf0[h] = v;
        out[(size_t)b * NS + h] = v;
    }
    __syncthreads();

    float* prev = buf0;
    float* cur = buf1;
    for (int l = 1; l < NL; ++l) {
        const float* e = eall + ((size_t)b * NL + l) * NS;
#pragma unroll
        for (int p = 0; p < 2; ++p) {
            const int h = tid + p * 1024;
            float v0 = wr[p][0] + prev[ix[p][0]];
            float v1 = wr[p][1] + prev[ix[p][1]];
            float v2 = wr[p][2] + prev[ix[p][2]];
            float v3 = wr[p][3] + prev[ix[p][3]];
            float v4 = wr[p][4] + prev[ix[p][4]];
            float v5 = wr[p][5] + prev[ix[p][5]];
            float v6 = wr[p][6] + prev[ix[p][6]];
            float m = fmaxf(fmaxf(fmaxf(v0, v1), fmaxf(v2, v3)),
                            fmaxf(fmaxf(v4, v5), v6));
            float s = __expf(v0 - m) + __expf(v1 - m) + __expf(v2 - m) + __expf(v3 - m) +
                      __expf(v4 - m) + __expf(v5 - m) + __expf(v6 - m);
            float v = e[h] + m + __logf(s);
            cur[h] = v;
            out[((size_t)l * NB + b) * NS + h] = v;
        }
        __syncthreads();
        float* tmp = prev; prev = cur; cur = tmp;
    }
}

// ---------------------------------------------------------------------------
extern "C" void kernel_launch(void* const* d_in, const int* in_sizes, int n_in,
                              void* d_out, int out_size, void* d_ws, size_t ws_size,
                              hipStream_t stream) {
    (void)in_sizes; (void)n_in; (void)out_size;
    const int* stories  = (const int*)d_in[0];
    // d_in[1] = story_length (== NL), unused
    const float* priors = (const float*)d_in[2];
    const float* trans  = (const float*)d_in[3];
    const float* em     = (const float*)d_in[4];
    float* out = (float*)d_out;

    float* emT  = (float*)d_ws;                    // [NT][NS]   16 MB
    float* eall = emT + (size_t)NT * NS;           // [NB*NL][NS] 2 MB
    float* xs   = eall + (size_t)NB * NL * NS;     // [NS][NT]   16 MB

    const size_t need = ((size_t)NT * NS + (size_t)NB * NL * NS + (size_t)NS * NT) * 4;
    if (ws_size >= need) {
        k_smoothA<<<dim3(8, 128), 256, 0, stream>>>(em, xs);
        k_smoothB<<<dim3(32, 32), 256, 0, stream>>>(xs, emT);
    } else {
        k_smooth<<<dim3(NT / TT, NZ), 256, 0, stream>>>(em, emT);
    }
    k_eall<<<dim3(NB * NL, 2), 256, 0, stream>>>(stories, emT, eall);
    k_forward<<<dim3(NB), 1024, 0, stream>>>(trans, priors, eall, out);
}